// Round 1
// baseline (179.602 us; speedup 1.0000x reference)
//
#include <hip/hip_runtime.h>

// StructuralLoss: predictions (64, 8192, 60) fp32.
// For each row of 60 features, 3 keys x 20 feats/key:
//   bid[l] = p[k*20 + 2l],  ask[l] = p[k*20 + 10 + 2l],  l = 0..4
//   ask_viol[l] = max(ask[l] - ask[l+1], 0)   l=0..3
//   bid_viol[l] = max(bid[l+1] - bid[l], 0)   l=0..3
//   spread_viol = max(bid[0] - ask[0], 0)
// total = (1/64) * sum over all rows of all 27 terms.

__global__ __launch_bounds__(256) void structural_loss_kernel(
    const float* __restrict__ pred, float* __restrict__ out, int nrows) {
    int r = blockIdx.x * blockDim.x + threadIdx.x;

    float s = 0.0f;
    if (r < nrows) {
        // Row base is r*60 floats = r*240 bytes -> 16B aligned, so float4 loads ok.
        const float4* rp = reinterpret_cast<const float4*>(pred + (size_t)r * 60);
        float p[60];
#pragma unroll
        for (int j = 0; j < 15; ++j) {
            float4 v = rp[j];
            p[4 * j + 0] = v.x;
            p[4 * j + 1] = v.y;
            p[4 * j + 2] = v.z;
            p[4 * j + 3] = v.w;
        }
#pragma unroll
        for (int k = 0; k < 3; ++k) {
            const float* q = p + k * 20;
#pragma unroll
            for (int l = 0; l < 4; ++l) {
                float av = q[10 + 2 * l] - q[12 + 2 * l]; // ask[l] - ask[l+1]
                float bv = q[2 * l + 2] - q[2 * l];       // bid[l+1] - bid[l]
                s += fmaxf(av, 0.0f) + fmaxf(bv, 0.0f);
            }
            s += fmaxf(q[0] - q[10], 0.0f); // spread: bid[0] - ask[0]
        }
    }

    // Wave (64-lane) shuffle reduction.
#pragma unroll
    for (int off = 32; off > 0; off >>= 1)
        s += __shfl_down(s, off, 64);

    __shared__ float wsum[4];
    int lane = threadIdx.x & 63;
    int wid = threadIdx.x >> 6;
    if (lane == 0) wsum[wid] = s;
    __syncthreads();
    if (threadIdx.x == 0) {
        float t = (wsum[0] + wsum[1] + wsum[2] + wsum[3]) * (1.0f / 64.0f);
        atomicAdd(out, t);
    }
}

extern "C" void kernel_launch(void* const* d_in, const int* in_sizes, int n_in,
                              void* d_out, int out_size, void* d_ws, size_t ws_size,
                              hipStream_t stream) {
    const float* pred = (const float*)d_in[0];
    float* out = (float*)d_out;

    int nrows = in_sizes[0] / 60; // 64 * 8192 = 524288
    int block = 256;
    int grid = (nrows + block - 1) / block; // 2048

    // d_out is re-poisoned to 0xAA before every timed launch -> zero it here.
    hipMemsetAsync(out, 0, sizeof(float), stream);
    structural_loss_kernel<<<grid, block, 0, stream>>>(pred, out, nrows);
}

// Round 2
// 177.645 us; speedup vs baseline: 1.0110x; 1.0110x over previous
//
#include <hip/hip_runtime.h>

// StructuralLoss: predictions (64, 8192, 60) fp32, rows of 60 floats = 15 float4s.
// Per key base b=20k within a row:
//   bid-viol pairs start at b+{0,2,4,6}:   max(p[i+2]-p[i], 0)
//   ask-viol pairs start at b+{10,12,14,16}: max(p[i]-p[i+2], 0)
//   spread at b: max(p[b]-p[b+10], 0)
// Thread per float4 f (elements 4f..4f+3). Case c = f%5 == (row-offset/4)%5:
//   pair A = (a.x, a.z) start at 4j:   dA = {+1,+1,0,-1,-1}[c]
//   pair B = (a.z, next.x) start 4j+2: dB = {+1,+1,-1,-1,0}[c]
//   spread (a.x, (f+2).z):             only c==0
// termA = max(dA*(a.z-a.x),0), termB = max(dB*(n0-a.z),0), termS = max(sS*(a.x-z2),0)

__global__ __launch_bounds__(256) void sl_partial(
    const float4* __restrict__ p4, const float* __restrict__ p,
    float* __restrict__ partial, unsigned nf4) {
    unsigned gid = blockIdx.x * 256u + threadIdx.x;
    unsigned stride = gridDim.x * 256u;

    float s = 0.0f;
    for (unsigned f = gid; f < nf4; f += stride) {
        float4 a = p4[f];
        unsigned fn = f + 1u; if (fn >= nf4) fn = nf4 - 1u;   // clamp: only unused slots OOB
        unsigned f2 = f + 2u; if (f2 >= nf4) f2 = nf4 - 1u;
        float n0 = p[(size_t)fn * 4u];       // x of f+1
        float z2 = p[(size_t)f2 * 4u + 2u];  // z of f+2

        unsigned c = f % 5u;
        float dA = (c < 2u) ? 1.0f : ((c == 2u) ? 0.0f : -1.0f);
        float dB = (c < 2u) ? 1.0f : ((c == 4u) ? 0.0f : -1.0f);
        float sS = (c == 0u) ? 1.0f : 0.0f;

        s += fmaxf(dA * (a.z - a.x), 0.0f);
        s += fmaxf(dB * (n0 - a.z), 0.0f);
        s += fmaxf(sS * (a.x - z2), 0.0f);
    }

    // wave (64) shuffle reduce, then 4-wave LDS reduce
#pragma unroll
    for (int off = 32; off > 0; off >>= 1) s += __shfl_down(s, off, 64);
    __shared__ float ws[4];
    if ((threadIdx.x & 63u) == 0u) ws[threadIdx.x >> 6] = s;
    __syncthreads();
    if (threadIdx.x == 0)
        partial[blockIdx.x] = ws[0] + ws[1] + ws[2] + ws[3];
}

__global__ __launch_bounds__(256) void sl_final(
    const float* __restrict__ partial, float* __restrict__ out, int n) {
    float s = 0.0f;
    for (int i = threadIdx.x; i < n; i += 256) s += partial[i];
#pragma unroll
    for (int off = 32; off > 0; off >>= 1) s += __shfl_down(s, off, 64);
    __shared__ float ws[4];
    if ((threadIdx.x & 63u) == 0u) ws[threadIdx.x >> 6] = s;
    __syncthreads();
    if (threadIdx.x == 0)
        out[0] = (ws[0] + ws[1] + ws[2] + ws[3]) * (1.0f / 64.0f);
}

extern "C" void kernel_launch(void* const* d_in, const int* in_sizes, int n_in,
                              void* d_out, int out_size, void* d_ws, size_t ws_size,
                              hipStream_t stream) {
    const float* pred = (const float*)d_in[0];
    float* out = (float*)d_out;
    float* partial = (float*)d_ws;  // 2048 floats, fully overwritten each launch

    unsigned nf4 = (unsigned)(in_sizes[0] / 4);  // 7,864,320
    int grid = 2048;                             // 524288 threads -> exactly 15 f4/thread

    sl_partial<<<grid, 256, 0, stream>>>(
        (const float4*)pred, pred, partial, nf4);
    sl_final<<<1, 256, 0, stream>>>(partial, out, grid);
}